// Round 5
// baseline (617.609 us; speedup 1.0000x reference)
//
#include <hip/hip_runtime.h>
#include <hip/hip_bf16.h>

using bf = __bf16;
typedef __attribute__((ext_vector_type(8))) __bf16 bf16x8;
typedef __attribute__((ext_vector_type(4))) float f32x4;

#define MFMA(a, b, c) __builtin_amdgcn_mfma_f32_16x16x32_bf16((a), (b), (c), 0, 0, 0)

static __device__ __forceinline__ bf16x8 load8(const bf* p) { return *(const bf16x8*)p; }

// fp32 -> bf16x8 on-the-fly conversion load (8 consecutive floats = 32 B)
static __device__ __forceinline__ bf16x8 load8(const float* p) {
    const f32x4 a = *(const f32x4*)p;
    const f32x4 b = *(const f32x4*)(p + 4);
    bf16x8 r;
#pragma unroll
    for (int i = 0; i < 4; ++i) { r[i] = (bf)a[i]; r[4 + i] = (bf)b[i]; }
    return r;
}

// C[m,n] = sum_k A[m,k] * W[n,k] + bias[n]  (+ res[m,n] if ADD_RES), fp32 accum.
// A: TA (fp32 inputs or bf16 intermediates). W/bias/res: fp32. C: TC (bf16 or fp32).
// Tile: block 128x128, 4 waves (2x2), wave 64x64 = 4x4 MFMA tiles of 16x16x32.
template <typename TA, typename TC, int ADD_RES>
__global__ __launch_bounds__(256) void gemm_bt(
    const TA* __restrict__ A, const float* __restrict__ W,
    const float* __restrict__ bias, const float* __restrict__ res,
    TC* __restrict__ C, int M, int N, int K)
{
    const int lane = threadIdx.x & 63;
    const int wave = threadIdx.x >> 6;
    const int lm = lane & 15;
    const int quad = lane >> 4;
    const int row0 = blockIdx.x * 128 + (wave >> 1) * 64;
    const int col0 = blockIdx.y * 128 + (wave & 1) * 64;

    f32x4 acc[4][4] = {};
    const TA* Ap = A + (size_t)(row0 + lm) * K + quad * 8;
    const float* Wp = W + (size_t)(col0 + lm) * K + quad * 8;

    for (int k0 = 0; k0 < K; k0 += 32) {
        bf16x8 a[4], b[4];
#pragma unroll
        for (int i = 0; i < 4; ++i) a[i] = load8(Ap + (size_t)i * 16 * K + k0);
#pragma unroll
        for (int j = 0; j < 4; ++j) b[j] = load8(Wp + (size_t)j * 16 * K + k0);
#pragma unroll
        for (int i = 0; i < 4; ++i)
#pragma unroll
            for (int j = 0; j < 4; ++j)
                acc[i][j] = MFMA(a[i], b[j], acc[i][j]);
    }

#pragma unroll
    for (int j = 0; j < 4; ++j) {
        const int col = col0 + j * 16 + lm;
        const float bv = bias[col];
#pragma unroll
        for (int i = 0; i < 4; ++i) {
#pragma unroll
            for (int r = 0; r < 4; ++r) {
                const int row = row0 + i * 16 + quad * 4 + r;
                float v = acc[i][j][r] + bv;
                if (ADD_RES) v += res[(size_t)row * N + col];
                C[(size_t)row * N + col] = (TC)v;
            }
        }
    }
}

// In-place L2 normalization of contiguous 64-element groups. One wave per group.
__global__ __launch_bounds__(256) void l2norm(bf* __restrict__ data)
{
    const long long g = (long long)blockIdx.x * 4 + (threadIdx.x >> 6);
    const int lane = threadIdx.x & 63;
    bf* p = data + g * 64 + lane;
    float v = (float)*p;
    float s = v * v;
#pragma unroll
    for (int m = 32; m; m >>= 1) s += __shfl_xor(s, m, 64);
    const float inv = 1.0f / fmaxf(sqrtf(s), 1e-12f);
    *p = (bf)(v * inv);
}

// One block per (bt, h). qn: (64,256,512) head h at cols h*64. kvn: (64,512,1024),
// k at cols h*64, v at cols 512+h*64. X: (64,256,512) merged-head output.
__global__ __launch_bounds__(256) void attn(
    const bf* __restrict__ qn, const bf* __restrict__ kvn, bf* __restrict__ X)
{
    __shared__ __attribute__((aligned(16))) bf vT[64 * 520];      // v^T, padded rows
    __shared__ __attribute__((aligned(16))) bf P[4][16 * 520];    // per-wave P tile

    const int bt = blockIdx.x >> 3;
    const int h = blockIdx.x & 7;
    const int tid = threadIdx.x;
    const int lane = tid & 63;
    const int wave = tid >> 6;
    const int lm = lane & 15;
    const int quad = lane >> 4;

    const bf* qh = qn + (size_t)bt * 256 * 512 + h * 64;    // row stride 512
    const bf* kh = kvn + (size_t)bt * 512 * 1024 + h * 64;  // row stride 1024
    const bf* vh = kh + 512;

    // stage v^T into LDS: vT[d][kk] = v[kk][d]
    for (int idx = tid; idx < 512 * 64; idx += 256) {
        const int kk = idx >> 6, d = idx & 63;
        vT[d * 520 + kk] = vh[(size_t)kk * 1024 + d];
    }
    __syncthreads();

    bf* Pw = &P[wave][0];
    const int r0w = wave * 64;

    for (int chunk = 0; chunk < 4; ++chunk) {
        const int r0 = r0w + chunk * 16;

        // Q A-fragments for this 16-row chunk (K=64 -> 2 steps)
        const bf* qp = qh + (size_t)(r0 + lm) * 512 + quad * 8;
        const bf16x8 a0 = load8(qp);
        const bf16x8 a1 = load8(qp + 32);

        // scores S (16 x 512) in fp32 regs: 32 col-tiles
        f32x4 s[32] = {};
        for (int nt = 0; nt < 32; ++nt) {
            const bf* kp = kh + (size_t)(nt * 16 + lm) * 1024 + quad * 8;
            s[nt] = MFMA(a0, load8(kp), s[nt]);
            s[nt] = MFMA(a1, load8(kp + 32), s[nt]);
        }

        // softmax over 512 cols; lane's rows are quad*4 + rr, cols nt*16 + lm
        float inv_l[4];
#pragma unroll
        for (int rr = 0; rr < 4; ++rr) {
            float mx = -1e30f;
#pragma unroll
            for (int nt = 0; nt < 32; ++nt) mx = fmaxf(mx, s[nt][rr]);
            mx = fmaxf(mx, __shfl_xor(mx, 1, 64));
            mx = fmaxf(mx, __shfl_xor(mx, 2, 64));
            mx = fmaxf(mx, __shfl_xor(mx, 4, 64));
            mx = fmaxf(mx, __shfl_xor(mx, 8, 64));
            float sum = 0.f;
#pragma unroll
            for (int nt = 0; nt < 32; ++nt) {
                const float e = __expf((s[nt][rr] - mx) * 0.125f);
                s[nt][rr] = e;
                sum += e;
            }
            sum += __shfl_xor(sum, 1, 64);
            sum += __shfl_xor(sum, 2, 64);
            sum += __shfl_xor(sum, 4, 64);
            sum += __shfl_xor(sum, 8, 64);
            inv_l[rr] = 1.0f / sum;
        }

        // write normalized P (bf16) to LDS: C-layout -> row-major
#pragma unroll
        for (int rr = 0; rr < 4; ++rr) {
            bf* pr = Pw + (quad * 4 + rr) * 520 + lm;
#pragma unroll
            for (int nt = 0; nt < 32; ++nt)
                pr[nt * 16] = (bf)(s[nt][rr] * inv_l[rr]);
        }

        __syncthreads();  // ensure P round-trip ordering (write -> A-layout read)

        // O (16 x 64) = P (16 x 512) @ v (512 x 64), reading P in A-layout, vT in B-layout
        f32x4 o[4] = {};
        for (int k0 = 0; k0 < 512; k0 += 32) {
            const bf16x8 ap = *(const bf16x8*)(Pw + lm * 520 + k0 + quad * 8);
#pragma unroll
            for (int dt = 0; dt < 4; ++dt) {
                const bf16x8 bv = *(const bf16x8*)(&vT[(dt * 16 + lm) * 520 + k0 + quad * 8]);
                o[dt] = MFMA(ap, bv, o[dt]);
            }
        }

        bf* Xp = X + ((size_t)bt * 256 + r0) * 512 + h * 64;
#pragma unroll
        for (int dt = 0; dt < 4; ++dt)
#pragma unroll
            for (int rr = 0; rr < 4; ++rr)
                Xp[(size_t)(quad * 4 + rr) * 512 + dt * 16 + lm] = (bf)o[dt][rr];

        __syncthreads();  // keep waves in lockstep before next chunk's P write
    }
}

extern "C" void kernel_launch(void* const* d_in, const int* in_sizes, int n_in,
                              void* d_out, int out_size, void* d_ws, size_t ws_size,
                              hipStream_t stream)
{
    const float* q   = (const float*)d_in[0];  // (8,8,256,512) fp32
    const float* kv  = (const float*)d_in[1];  // (8,8,512,512) fp32
    const float* Wq  = (const float*)d_in[2];  // (512,512) fp32
    const float* bq  = (const float*)d_in[3];  // (512) fp32
    const float* Wkv = (const float*)d_in[4];  // (1024,512) fp32
    const float* bkv = (const float*)d_in[5];  // (1024) fp32
    const float* Wm  = (const float*)d_in[6];  // (512,512) fp32
    const float* bm  = (const float*)d_in[7];  // (512) fp32
    float* out = (float*)d_out;                // (8,8,256,512) fp32

    char* ws = (char*)d_ws;
    bf* qn  = (bf*)ws;                          // 16384 x 512  bf16 (16 MiB)
    bf* kvn = (bf*)(ws + (size_t)(16 << 20));   // 32768 x 1024 bf16 (64 MiB)
    bf* X   = (bf*)(ws + (size_t)(80 << 20));   // 16384 x 512  bf16 (16 MiB)

    // Q projection: (16384,512) @ Wq^T + bq
    gemm_bt<float, bf, 0><<<dim3(128, 4), 256, 0, stream>>>(q, Wq, bq, nullptr, qn, 16384, 512, 512);
    // KV projection: (32768,512) @ Wkv^T + bkv
    gemm_bt<float, bf, 0><<<dim3(256, 8), 256, 0, stream>>>(kv, Wkv, bkv, nullptr, kvn, 32768, 1024, 512);
    // L2 norm per 64-wide head group (in place)
    l2norm<<<dim3(131072 / 4), 256, 0, stream>>>(qn);
    l2norm<<<dim3(524288 / 4), 256, 0, stream>>>(kvn);
    // fused cosine attention per (bt, h)
    attn<<<dim3(512), 256, 0, stream>>>(qn, kvn, X);
    // output projection + bias + residual (fp32 output)
    gemm_bt<bf, float, 1><<<dim3(128, 4), 256, 0, stream>>>(X, Wm, bm, q, out, 16384, 512, 512);
}

// Round 6
// 316.614 us; speedup vs baseline: 1.9507x; 1.9507x over previous
//
#include <hip/hip_runtime.h>
#include <hip/hip_bf16.h>

using bf = __bf16;
typedef __attribute__((ext_vector_type(8))) __bf16 bf16x8;
typedef __attribute__((ext_vector_type(4))) float f32x4;

#define MFMA(a, b, c) __builtin_amdgcn_mfma_f32_16x16x32_bf16((a), (b), (c), 0, 0, 0)
#define GLL16(g, s)                                                         \
    __builtin_amdgcn_global_load_lds(                                       \
        (const __attribute__((address_space(1))) void*)(g),                 \
        (__attribute__((address_space(3))) void*)(s), 16, 0, 0)

// ---------------- fp32 -> bf16 convert, 8 elems/thread ----------------
__global__ __launch_bounds__(256) void cvt8(const float* __restrict__ s,
                                            bf* __restrict__ d, int n8)
{
    const int i = blockIdx.x * 256 + threadIdx.x;
    if (i >= n8) return;
    const f32x4 a = ((const f32x4*)s)[2 * i];
    const f32x4 b = ((const f32x4*)s)[2 * i + 1];
    bf16x8 r;
#pragma unroll
    for (int k = 0; k < 4; ++k) { r[k] = (bf)a[k]; r[4 + k] = (bf)b[k]; }
    ((bf16x8*)d)[i] = r;
}

// ---------------- m97-style bf16 GEMM: C = A @ W^T + bias (+epilogue) ----------------
// EPI 0: bias + L2-normalize each 64-col group per row, bf16 out (projections)
// EPI 1: bias + fp32 residual, fp32 out (output projection)
// Block 128x128, 4 waves 2x2, wave 64x64 = 4x4 MFMA 16x16x32. BK=32.
template <int EPI>
__global__ __launch_bounds__(256) void gemm128(
    const bf* __restrict__ A, const bf* __restrict__ W,
    const float* __restrict__ bias, const float* __restrict__ res,
    void* __restrict__ Cout, int M, int N, int K)
{
    __shared__ __attribute__((aligned(16))) bf As[128 * 32];
    __shared__ __attribute__((aligned(16))) bf Bs[128 * 32];

    const int lane = threadIdx.x & 63;
    const int wave = threadIdx.x >> 6;
    const int lm = lane & 15;
    const int quad = lane >> 4;
    const int row0 = blockIdx.x * 128, col0 = blockIdx.y * 128;
    const int wrow = (wave >> 1) * 64, wcol = (wave & 1) * 64;

    // staging map: wave covers 32 rows (2 instrs x 16 rows); lane -> (row sr, 16B chunk sc)
    const int sr = lane >> 2;            // 0..15
    const int sc = (lane & 3) * 8;       // elem offset 0,8,16,24
    const bf* Ag = A + (size_t)(row0 + wave * 32 + sr) * K + sc;
    const bf* Wg = W + (size_t)(col0 + wave * 32 + sr) * K + sc;
    bf* AsW = As + wave * 1024;          // wave's 1024-elem LDS region (row-major [32][32])
    bf* BsW = Bs + wave * 1024;

    f32x4 acc[4][4] = {};

    for (int k0 = 0; k0 < K; k0 += 32) {
        GLL16(Ag + k0, AsW);
        GLL16(Ag + (size_t)16 * K + k0, AsW + 512);
        GLL16(Wg + k0, BsW);
        GLL16(Wg + (size_t)16 * K + k0, BsW + 512);
        __syncthreads();

        bf16x8 a[4], b[4];
#pragma unroll
        for (int i = 0; i < 4; ++i)
            a[i] = *(const bf16x8*)(As + (wrow + i * 16 + lm) * 32 + quad * 8);
#pragma unroll
        for (int j = 0; j < 4; ++j)
            b[j] = *(const bf16x8*)(Bs + (wcol + j * 16 + lm) * 32 + quad * 8);
#pragma unroll
        for (int i = 0; i < 4; ++i)
#pragma unroll
            for (int j = 0; j < 4; ++j)
                acc[i][j] = MFMA(a[i], b[j], acc[i][j]);
        __syncthreads();
    }

    float bv[4];
#pragma unroll
    for (int j = 0; j < 4; ++j) bv[j] = bias[col0 + wcol + j * 16 + lm];

    if (EPI == 0) {
        bf* C = (bf*)Cout;
#pragma unroll
        for (int i = 0; i < 4; ++i) {
#pragma unroll
            for (int r = 0; r < 4; ++r) {
                float v[4];
                float ss = 0.f;
#pragma unroll
                for (int j = 0; j < 4; ++j) {
                    const float x = acc[i][j][r] + bv[j];
                    v[j] = x;
                    ss += x * x;
                }
                ss += __shfl_xor(ss, 1, 64);
                ss += __shfl_xor(ss, 2, 64);
                ss += __shfl_xor(ss, 4, 64);
                ss += __shfl_xor(ss, 8, 64);
                const float inv = 1.0f / fmaxf(sqrtf(ss), 1e-12f);
                const int row = row0 + wrow + i * 16 + quad * 4 + r;
#pragma unroll
                for (int j = 0; j < 4; ++j)
                    C[(size_t)row * N + col0 + wcol + j * 16 + lm] = (bf)(v[j] * inv);
            }
        }
    } else {
        float* C = (float*)Cout;
#pragma unroll
        for (int i = 0; i < 4; ++i) {
#pragma unroll
            for (int r = 0; r < 4; ++r) {
                const int row = row0 + wrow + i * 16 + quad * 4 + r;
#pragma unroll
                for (int j = 0; j < 4; ++j) {
                    const size_t idx = (size_t)row * N + col0 + wcol + j * 16 + lm;
                    C[idx] = acc[i][j][r] + bv[j] + res[idx];
                }
            }
        }
    }
}

// ---------------- fused cosine attention, one block per (bt, h) ----------------
// qn: (64,256,512) bf16, head h at cols h*64. kvn: (64,512,1024) bf16, k at h*64, v at 512+h*64.
// X: (64,256,512) bf16 merged-head output.
__global__ __launch_bounds__(256) void attn(
    const bf* __restrict__ qn, const bf* __restrict__ kvn, bf* __restrict__ X)
{
    __shared__ __attribute__((aligned(16))) bf kS[512 * 72];   // [key][72] (64 used)
    __shared__ __attribute__((aligned(16))) bf vT[64 * 520];   // [d][520] (512 used)
    __shared__ __attribute__((aligned(16))) bf Ps[4][16 * 40]; // per-wave P slice [16][40]

    const int bt = blockIdx.x >> 3;
    const int h = blockIdx.x & 7;
    const int tid = threadIdx.x;
    const int lane = tid & 63;
    const int wave = tid >> 6;
    const int lm = lane & 15;
    const int quad = lane >> 4;

    const bf* qh = qn + (size_t)bt * 256 * 512 + h * 64;    // row stride 512
    const bf* kh = kvn + (size_t)bt * 512 * 1024 + h * 64;  // row stride 1024
    const bf* vh = kh + 512;

    // stage K (row-major) and V^T
    {
        const int rr = tid >> 3;           // 0..31
        const int c8 = (tid & 7) * 8;      // 0..56
        for (int it = 0; it < 16; ++it) {
            const int row = it * 32 + rr;
            *(bf16x8*)(&kS[row * 72 + c8]) = *(const bf16x8*)(kh + (size_t)row * 1024 + c8);
        }
        for (int it = 0; it < 16; ++it) {
            const int kk = it * 32 + rr;
            const bf16x8 vv = *(const bf16x8*)(vh + (size_t)kk * 1024 + c8);
#pragma unroll
            for (int j = 0; j < 8; ++j) vT[(c8 + j) * 520 + kk] = vv[j];
        }
    }
    __syncthreads();

    bf* Pw = &Ps[wave][0];

    for (int chunk = 0; chunk < 4; ++chunk) {
        const int r0 = wave * 64 + chunk * 16;

        // Q A-fragments (16 rows, K=64 -> 2 frags)
        const bf* qp = qh + (size_t)(r0 + lm) * 512 + quad * 8;
        const bf16x8 a0 = *(const bf16x8*)qp;
        const bf16x8 a1 = *(const bf16x8*)(qp + 32);

        // S (16 x 512) in regs
        f32x4 s[32];
#pragma unroll
        for (int nt = 0; nt < 32; ++nt) {
            const bf16x8 k0f = *(const bf16x8*)(&kS[(nt * 16 + lm) * 72 + quad * 8]);
            const bf16x8 k1f = *(const bf16x8*)(&kS[(nt * 16 + lm) * 72 + 32 + quad * 8]);
            f32x4 z = {};
            z = MFMA(a0, k0f, z);
            s[nt] = MFMA(a1, k1f, z);
        }

        // row max
        float mx[4];
#pragma unroll
        for (int rr = 0; rr < 4; ++rr) {
            float m = s[0][rr];
#pragma unroll
            for (int nt = 1; nt < 32; ++nt) m = fmaxf(m, s[nt][rr]);
            m = fmaxf(m, __shfl_xor(m, 1, 64));
            m = fmaxf(m, __shfl_xor(m, 2, 64));
            m = fmaxf(m, __shfl_xor(m, 4, 64));
            m = fmaxf(m, __shfl_xor(m, 8, 64));
            mx[rr] = m;
        }

        // stream P (unnormalized exp) through 16x32 LDS slices, accumulate O and row sums
        f32x4 o[4] = {};
        float sum[4] = {0.f, 0.f, 0.f, 0.f};
        for (int ntp = 0; ntp < 16; ++ntp) {
#pragma unroll
            for (int t = 0; t < 2; ++t) {
#pragma unroll
                for (int rr = 0; rr < 4; ++rr) {
                    const float e = __expf((s[2 * ntp + t][rr] - mx[rr]) * 0.125f);
                    sum[rr] += e;
                    Pw[(quad * 4 + rr) * 40 + t * 16 + lm] = (bf)e;
                }
            }
            // P slice in A-layout; vT k-slice = ntp*32
            const bf16x8 ap = *(const bf16x8*)(&Pw[lm * 40 + quad * 8]);
#pragma unroll
            for (int dt = 0; dt < 4; ++dt) {
                const bf16x8 bv = *(const bf16x8*)(&vT[(dt * 16 + lm) * 520 + ntp * 32 + quad * 8]);
                o[dt] = MFMA(ap, bv, o[dt]);
            }
        }

        float inv_l[4];
#pragma unroll
        for (int rr = 0; rr < 4; ++rr) {
            float sm = sum[rr];
            sm += __shfl_xor(sm, 1, 64);
            sm += __shfl_xor(sm, 2, 64);
            sm += __shfl_xor(sm, 4, 64);
            sm += __shfl_xor(sm, 8, 64);
            inv_l[rr] = 1.0f / sm;
        }

        bf* Xp = X + ((size_t)bt * 256 + r0) * 512 + h * 64;
#pragma unroll
        for (int dt = 0; dt < 4; ++dt)
#pragma unroll
            for (int rr = 0; rr < 4; ++rr)
                Xp[(size_t)(quad * 4 + rr) * 512 + dt * 16 + lm] = (bf)(o[dt][rr] * inv_l[rr]);
    }
}

extern "C" void kernel_launch(void* const* d_in, const int* in_sizes, int n_in,
                              void* d_out, int out_size, void* d_ws, size_t ws_size,
                              hipStream_t stream)
{
    const float* q   = (const float*)d_in[0];  // (8,8,256,512) fp32
    const float* kv  = (const float*)d_in[1];  // (8,8,512,512) fp32
    const float* Wq  = (const float*)d_in[2];  // (512,512) fp32
    const float* bq  = (const float*)d_in[3];  // (512) fp32
    const float* Wkv = (const float*)d_in[4];  // (1024,512) fp32
    const float* bkv = (const float*)d_in[5];  // (1024) fp32
    const float* Wm  = (const float*)d_in[6];  // (512,512) fp32
    const float* bm  = (const float*)d_in[7];  // (512) fp32
    float* out = (float*)d_out;                // (8,8,256,512) fp32 (32 MiB)

    // Workspace layout (<= 96 MiB, proven safe) + d_out used as early scratch:
    char* ws = (char*)d_ws;
    bf* kvb = (bf*)ws;                          // [0,32 MiB)  kv bf16 (dead after KV-proj)
    bf* kvn = (bf*)(ws + (size_t)(32 << 20));   // [32,96 MiB) normalized kv heads
    bf* wqb = (bf*)ws;                          // [0,0.5 MiB) Wq bf16 (after kvb dead)
    bf* wmb = (bf*)(ws + (size_t)(16 << 20));   // [16,16.5 MiB) Wm bf16 (after kvb dead)
    bf* X   = (bf*)ws;                          // [0,16 MiB)  attn output (after wqb dead)
    char* dob = (char*)d_out;
    bf* wkvb = (bf*)dob;                        // d_out[0,1 MiB) Wkv bf16 (dead after KV-proj)
    bf* qb   = (bf*)dob;                        // d_out[0,16 MiB) q bf16 (overwrites wkvb)
    bf* qn   = (bf*)(dob + (size_t)(16 << 20)); // d_out[16,32 MiB) normalized q heads

    // 1. kv -> bf16; Wkv -> bf16 (in d_out)
    cvt8<<<dim3(8192), 256, 0, stream>>>(kv, kvb, 2097152);
    cvt8<<<dim3(256), 256, 0, stream>>>(Wkv, wkvb, 65536);
    // 2. KV projection + bias + fused L2-norm per head group
    gemm128<0><<<dim3(256, 8), 256, 0, stream>>>(kvb, wkvb, bkv, nullptr, kvn, 32768, 1024, 512);
    // 3. q -> bf16 (into d_out, kills wkvb); Wq, Wm -> bf16 (into ws, kvb dead)
    cvt8<<<dim3(4096), 256, 0, stream>>>(q, qb, 1048576);
    cvt8<<<dim3(128), 256, 0, stream>>>(Wq, wqb, 32768);
    cvt8<<<dim3(128), 256, 0, stream>>>(Wm, wmb, 32768);
    // 4. Q projection + bias + fused L2-norm
    gemm128<0><<<dim3(128, 4), 256, 0, stream>>>(qb, wqb, bq, nullptr, qn, 16384, 512, 512);
    // 5. fused cosine attention (kills wqb region via X write)
    attn<<<dim3(512), 256, 0, stream>>>(qn, kvn, X);
    // 6. output projection + bias + fp32 residual -> fp32 out (rewrites all of d_out)
    gemm128<1><<<dim3(128, 4), 256, 0, stream>>>(X, wmb, bm, q, out, 16384, 512, 512);
}

// Round 7
// 306.782 us; speedup vs baseline: 2.0132x; 1.0321x over previous
//
#include <hip/hip_runtime.h>
#include <hip/hip_bf16.h>

using bf = __bf16;
typedef __attribute__((ext_vector_type(8))) __bf16 bf16x8;
typedef __attribute__((ext_vector_type(4))) float f32x4;

#define MFMA(a, b, c) __builtin_amdgcn_mfma_f32_16x16x32_bf16((a), (b), (c), 0, 0, 0)
#define GLL16(g, s)                                                         \
    __builtin_amdgcn_global_load_lds(                                       \
        (const __attribute__((address_space(1))) void*)(g),                 \
        (__attribute__((address_space(3))) void*)(s), 16, 0, 0)

// ---------------- fp32 -> bf16 converts (merged, 8 elems/thread) ----------------
static __device__ __forceinline__ void cvt_one(const float* __restrict__ s,
                                               bf* __restrict__ d, int i)
{
    const f32x4 a = ((const f32x4*)s)[2 * i];
    const f32x4 b = ((const f32x4*)s)[2 * i + 1];
    bf16x8 r;
#pragma unroll
    for (int k = 0; k < 4; ++k) { r[k] = (bf)a[k]; r[4 + k] = (bf)b[k]; }
    ((bf16x8*)d)[i] = r;
}

__global__ __launch_bounds__(256) void cvt2(const float* __restrict__ s1, bf* __restrict__ d1, int n1,
                                            const float* __restrict__ s2, bf* __restrict__ d2, int n2)
{
    int i = blockIdx.x * 256 + threadIdx.x;
    if (i < n1) { cvt_one(s1, d1, i); return; }
    i -= n1;
    if (i < n2) cvt_one(s2, d2, i);
}

__global__ __launch_bounds__(256) void cvt3(const float* __restrict__ s1, bf* __restrict__ d1, int n1,
                                            const float* __restrict__ s2, bf* __restrict__ d2, int n2,
                                            const float* __restrict__ s3, bf* __restrict__ d3, int n3)
{
    int i = blockIdx.x * 256 + threadIdx.x;
    if (i < n1) { cvt_one(s1, d1, i); return; }
    i -= n1;
    if (i < n2) { cvt_one(s2, d2, i); return; }
    i -= n2;
    if (i < n3) cvt_one(s3, d3, i);
}

// ---------------- m97-style bf16 GEMM: C = A @ W^T + bias (+epilogue) ----------------
// EPI 0: bias + L2-normalize each 64-col group per row, bf16 out (projections)
// EPI 1: bias + fp32 residual, fp32 out (output projection)
// Block 128x128, 4 waves 2x2, wave 64x64 = 4x4 MFMA 16x16x32. BK=32.
template <int EPI>
__global__ __launch_bounds__(256) void gemm128(
    const bf* __restrict__ A, const bf* __restrict__ W,
    const float* __restrict__ bias, const float* __restrict__ res,
    void* __restrict__ Cout, int M, int N, int K)
{
    __shared__ __attribute__((aligned(16))) bf As[128 * 32];
    __shared__ __attribute__((aligned(16))) bf Bs[128 * 32];

    const int lane = threadIdx.x & 63;
    const int wave = threadIdx.x >> 6;
    const int lm = lane & 15;
    const int quad = lane >> 4;
    const int row0 = blockIdx.x * 128, col0 = blockIdx.y * 128;
    const int wrow = (wave >> 1) * 64, wcol = (wave & 1) * 64;

    const int sr = lane >> 2;            // 0..15
    const int sc = (lane & 3) * 8;       // elem offset 0,8,16,24
    const bf* Ag = A + (size_t)(row0 + wave * 32 + sr) * K + sc;
    const bf* Wg = W + (size_t)(col0 + wave * 32 + sr) * K + sc;
    bf* AsW = As + wave * 1024;
    bf* BsW = Bs + wave * 1024;

    f32x4 acc[4][4] = {};

    for (int k0 = 0; k0 < K; k0 += 32) {
        GLL16(Ag + k0, AsW);
        GLL16(Ag + (size_t)16 * K + k0, AsW + 512);
        GLL16(Wg + k0, BsW);
        GLL16(Wg + (size_t)16 * K + k0, BsW + 512);
        __syncthreads();

        bf16x8 a[4], b[4];
#pragma unroll
        for (int i = 0; i < 4; ++i)
            a[i] = *(const bf16x8*)(As + (wrow + i * 16 + lm) * 32 + quad * 8);
#pragma unroll
        for (int j = 0; j < 4; ++j)
            b[j] = *(const bf16x8*)(Bs + (wcol + j * 16 + lm) * 32 + quad * 8);
#pragma unroll
        for (int i = 0; i < 4; ++i)
#pragma unroll
            for (int j = 0; j < 4; ++j)
                acc[i][j] = MFMA(a[i], b[j], acc[i][j]);
        __syncthreads();
    }

    float bv[4];
#pragma unroll
    for (int j = 0; j < 4; ++j) bv[j] = bias[col0 + wcol + j * 16 + lm];

    if (EPI == 0) {
        bf* C = (bf*)Cout;
#pragma unroll
        for (int i = 0; i < 4; ++i) {
#pragma unroll
            for (int r = 0; r < 4; ++r) {
                float v[4];
                float ss = 0.f;
#pragma unroll
                for (int j = 0; j < 4; ++j) {
                    const float x = acc[i][j][r] + bv[j];
                    v[j] = x;
                    ss += x * x;
                }
                ss += __shfl_xor(ss, 1, 64);
                ss += __shfl_xor(ss, 2, 64);
                ss += __shfl_xor(ss, 4, 64);
                ss += __shfl_xor(ss, 8, 64);
                const float inv = 1.0f / fmaxf(sqrtf(ss), 1e-12f);
                const int row = row0 + wrow + i * 16 + quad * 4 + r;
#pragma unroll
                for (int j = 0; j < 4; ++j)
                    C[(size_t)row * N + col0 + wcol + j * 16 + lm] = (bf)(v[j] * inv);
            }
        }
    } else {
        float* C = (float*)Cout;
#pragma unroll
        for (int i = 0; i < 4; ++i) {
#pragma unroll
            for (int r = 0; r < 4; ++r) {
                const int row = row0 + wrow + i * 16 + quad * 4 + r;
#pragma unroll
                for (int j = 0; j < 4; ++j) {
                    const size_t idx = (size_t)row * N + col0 + wcol + j * 16 + lm;
                    C[idx] = acc[i][j][r] + bv[j] + res[idx];
                }
            }
        }
    }
}

// ---------------- flash-style fused cosine attention ----------------
// Grid 2048: blockIdx = qb*512 + bt*8 + h (same-(bt,h) blocks 512 apart -> same XCD).
// Block: 256 thr, 4 waves; each wave owns 16 q-rows of the block's 64-row slice.
// Online softmax over 4 key-tiles of 128. LDS 40 KB -> 4 blocks/CU @ 4 waves/SIMD.
__global__ __launch_bounds__(256, 4) void attn(
    const bf* __restrict__ qn, const bf* __restrict__ kvn, bf* __restrict__ X)
{
    __shared__ __attribute__((aligned(16))) bf Kt[128 * 72];   // key tile [key][72]
    __shared__ __attribute__((aligned(16))) bf Vt[64 * 136];   // V^T tile [d][136]
    __shared__ __attribute__((aligned(16))) bf Ps[4][16 * 40]; // per-wave P slice

    const int qb = blockIdx.x >> 9;
    const int rb = blockIdx.x & 511;
    const int bt = rb >> 3;
    const int h = rb & 7;
    const int tid = threadIdx.x;
    const int lane = tid & 63;
    const int wave = tid >> 6;
    const int lm = lane & 15;
    const int quad = lane >> 4;

    const bf* qh = qn + ((size_t)bt * 256 + qb * 64) * 512 + h * 64;  // row stride 512
    const bf* kh = kvn + (size_t)bt * 512 * 1024 + h * 64;            // row stride 1024
    const bf* vh = kh + 512;

    // Q A-fragments for this wave's 16 rows (loaded once)
    const bf* qp = qh + (size_t)(wave * 16 + lm) * 512 + quad * 8;
    const bf16x8 a0 = *(const bf16x8*)qp;
    const bf16x8 a1 = *(const bf16x8*)(qp + 32);

    f32x4 o[4] = {};
    float mrow[4] = {-1e30f, -1e30f, -1e30f, -1e30f};
    float lrow[4] = {};

    const int srow = tid >> 1;        // 0..127: key row staged by this thread
    const int sseg = (tid & 1) * 32;  // elem offset within the 64-wide head

    for (int t = 0; t < 4; ++t) {
        // ---- stage K tile (row-major) and V^T tile ----
        {
            const bf* kr = kh + (size_t)(t * 128 + srow) * 1024 + sseg;
            bf* kd = Kt + srow * 72 + sseg;
#pragma unroll
            for (int j = 0; j < 4; ++j)
                *(bf16x8*)(kd + j * 8) = *(const bf16x8*)(kr + j * 8);

            const bf* vr = vh + (size_t)(t * 128 + srow) * 1024 + sseg;
            bf16x8 vv[4];
#pragma unroll
            for (int j = 0; j < 4; ++j) vv[j] = *(const bf16x8*)(vr + j * 8);
#pragma unroll
            for (int j = 0; j < 4; ++j)
#pragma unroll
                for (int e = 0; e < 8; ++e)
                    Vt[(sseg + j * 8 + e) * 136 + srow] = vv[j][e];
        }
        __syncthreads();

        // ---- scores vs this tile's 128 keys ----
        f32x4 s[8];
#pragma unroll
        for (int nt = 0; nt < 8; ++nt) {
            const bf16x8 k0 = *(const bf16x8*)(&Kt[(nt * 16 + lm) * 72 + quad * 8]);
            const bf16x8 k1 = *(const bf16x8*)(&Kt[(nt * 16 + lm) * 72 + 32 + quad * 8]);
            f32x4 z = {};
            z = MFMA(a0, k0, z);
            s[nt] = MFMA(a1, k1, z);
        }

        // ---- online-softmax merge ----
        float alpha[4], mnew[4];
#pragma unroll
        for (int rr = 0; rr < 4; ++rr) {
            float m = s[0][rr];
#pragma unroll
            for (int nt = 1; nt < 8; ++nt) m = fmaxf(m, s[nt][rr]);
            m = fmaxf(m, __shfl_xor(m, 1, 64));
            m = fmaxf(m, __shfl_xor(m, 2, 64));
            m = fmaxf(m, __shfl_xor(m, 4, 64));
            m = fmaxf(m, __shfl_xor(m, 8, 64));
            const float mn = fmaxf(mrow[rr], m);
            alpha[rr] = __expf((mrow[rr] - mn) * 0.125f);
            mnew[rr] = mn;
            mrow[rr] = mn;
        }
#pragma unroll
        for (int dt = 0; dt < 4; ++dt)
#pragma unroll
            for (int rr = 0; rr < 4; ++rr) o[dt][rr] *= alpha[rr];

        // ---- P slices through LDS, accumulate PV ----
        float tsum[4] = {};
        bf* Pw = &Ps[wave][0];
        for (int ntp = 0; ntp < 4; ++ntp) {
#pragma unroll
            for (int tt = 0; tt < 2; ++tt)
#pragma unroll
                for (int rr = 0; rr < 4; ++rr) {
                    const float e = __expf((s[ntp * 2 + tt][rr] - mnew[rr]) * 0.125f);
                    tsum[rr] += e;
                    Pw[(quad * 4 + rr) * 40 + tt * 16 + lm] = (bf)e;
                }
            const bf16x8 ap = *(const bf16x8*)(&Pw[lm * 40 + quad * 8]);
#pragma unroll
            for (int dt = 0; dt < 4; ++dt) {
                const bf16x8 bv = *(const bf16x8*)(&Vt[(dt * 16 + lm) * 136 + ntp * 32 + quad * 8]);
                o[dt] = MFMA(ap, bv, o[dt]);
            }
        }
#pragma unroll
        for (int rr = 0; rr < 4; ++rr) {
            float sm = tsum[rr];
            sm += __shfl_xor(sm, 1, 64);
            sm += __shfl_xor(sm, 2, 64);
            sm += __shfl_xor(sm, 4, 64);
            sm += __shfl_xor(sm, 8, 64);
            lrow[rr] = lrow[rr] * alpha[rr] + sm;
        }
        __syncthreads();  // Kt/Vt reused next tile
    }

    float inv[4];
#pragma unroll
    for (int rr = 0; rr < 4; ++rr) inv[rr] = 1.0f / lrow[rr];
    bf* Xp = X + ((size_t)bt * 256 + qb * 64 + wave * 16) * 512 + h * 64;
#pragma unroll
    for (int dt = 0; dt < 4; ++dt)
#pragma unroll
        for (int rr = 0; rr < 4; ++rr)
            Xp[(size_t)(quad * 4 + rr) * 512 + dt * 16 + lm] = (bf)(o[dt][rr] * inv[rr]);
}

extern "C" void kernel_launch(void* const* d_in, const int* in_sizes, int n_in,
                              void* d_out, int out_size, void* d_ws, size_t ws_size,
                              hipStream_t stream)
{
    const float* q   = (const float*)d_in[0];  // (8,8,256,512) fp32
    const float* kv  = (const float*)d_in[1];  // (8,8,512,512) fp32
    const float* Wq  = (const float*)d_in[2];  // (512,512) fp32
    const float* bq  = (const float*)d_in[3];  // (512) fp32
    const float* Wkv = (const float*)d_in[4];  // (1024,512) fp32
    const float* bkv = (const float*)d_in[5];  // (1024) fp32
    const float* Wm  = (const float*)d_in[6];  // (512,512) fp32
    const float* bm  = (const float*)d_in[7];  // (512) fp32
    float* out = (float*)d_out;                // (8,8,256,512) fp32 (32 MiB)

    char* ws = (char*)d_ws;
    bf* kvb = (bf*)ws;                          // [0,32 MiB)  kv bf16 (dead after KV-proj)
    bf* kvn = (bf*)(ws + (size_t)(32 << 20));   // [32,96 MiB) normalized kv heads
    bf* wqb = (bf*)ws;                          // [0,0.5 MiB) Wq bf16 (after kvb dead)
    bf* wmb = (bf*)(ws + (size_t)(16 << 20));   // [16,16.5 MiB) Wm bf16 (after kvb dead)
    bf* X   = (bf*)ws;                          // [0,16 MiB)  attn output (after wqb dead)
    char* dob = (char*)d_out;
    bf* wkvb = (bf*)dob;                        // d_out[0,1 MiB) Wkv bf16 (dead after KV-proj)
    bf* qb   = (bf*)dob;                        // d_out[0,16 MiB) q bf16 (overwrites wkvb)
    bf* qn   = (bf*)(dob + (size_t)(16 << 20)); // d_out[16,32 MiB) normalized q heads

    // 1. kv + Wkv -> bf16
    cvt2<<<dim3(8448), 256, 0, stream>>>(kv, kvb, 2097152, Wkv, wkvb, 65536);
    // 2. KV projection + bias + fused L2-norm per head group
    gemm128<0><<<dim3(256, 8), 256, 0, stream>>>(kvb, wkvb, bkv, nullptr, kvn, 32768, 1024, 512);
    // 3. q, Wq, Wm -> bf16 (qb kills wkvb; wqb/wmb reuse dead kvb space)
    cvt3<<<dim3(4352), 256, 0, stream>>>(q, qb, 1048576, Wq, wqb, 32768, Wm, wmb, 32768);
    // 4. Q projection + bias + fused L2-norm
    gemm128<0><<<dim3(128, 4), 256, 0, stream>>>(qb, wqb, bq, nullptr, qn, 16384, 512, 512);
    // 5. flash-style cosine attention
    attn<<<dim3(2048), 256, 0, stream>>>(qn, kvn, X);
    // 6. output projection + bias + fp32 residual -> fp32 out (rewrites all of d_out)
    gemm128<1><<<dim3(128, 4), 256, 0, stream>>>(X, wmb, bm, q, out, 16384, 512, 512);
}

// Round 8
// 282.798 us; speedup vs baseline: 2.1839x; 1.0848x over previous
//
#include <hip/hip_runtime.h>
#include <hip/hip_bf16.h>

using bf = __bf16;
typedef __attribute__((ext_vector_type(8))) __bf16 bf16x8;
typedef __attribute__((ext_vector_type(4))) float f32x4;

#define MFMA(a, b, c) __builtin_amdgcn_mfma_f32_16x16x32_bf16((a), (b), (c), 0, 0, 0)
#define GLL16(g, s)                                                         \
    __builtin_amdgcn_global_load_lds(                                       \
        (const __attribute__((address_space(1))) void*)(g),                 \
        (__attribute__((address_space(3))) void*)(s), 16, 0, 0)

// ---------------- fp32 -> bf16 converts (merged, 8 elems/thread) ----------------
static __device__ __forceinline__ void cvt_one(const float* __restrict__ s,
                                               bf* __restrict__ d, int i)
{
    const f32x4 a = ((const f32x4*)s)[2 * i];
    const f32x4 b = ((const f32x4*)s)[2 * i + 1];
    bf16x8 r;
#pragma unroll
    for (int k = 0; k < 4; ++k) { r[k] = (bf)a[k]; r[4 + k] = (bf)b[k]; }
    ((bf16x8*)d)[i] = r;
}

__global__ __launch_bounds__(256) void cvt2(const float* __restrict__ s1, bf* __restrict__ d1, int n1,
                                            const float* __restrict__ s2, bf* __restrict__ d2, int n2)
{
    int i = blockIdx.x * 256 + threadIdx.x;
    if (i < n1) { cvt_one(s1, d1, i); return; }
    i -= n1;
    if (i < n2) cvt_one(s2, d2, i);
}

__global__ __launch_bounds__(256) void cvt3(const float* __restrict__ s1, bf* __restrict__ d1, int n1,
                                            const float* __restrict__ s2, bf* __restrict__ d2, int n2,
                                            const float* __restrict__ s3, bf* __restrict__ d3, int n3)
{
    int i = blockIdx.x * 256 + threadIdx.x;
    if (i < n1) { cvt_one(s1, d1, i); return; }
    i -= n1;
    if (i < n2) { cvt_one(s2, d2, i); return; }
    i -= n2;
    if (i < n3) cvt_one(s3, d3, i);
}

// ---------------- m97-style bf16 GEMM: C = A @ W^T + bias (+epilogue) ----------------
// EPI 0: bias + L2-norm per 64-col head group, bf16 out in HEAD-MAJOR layout
//        C[((bt*GH + g)*R + r)*64 + d]  where bt=row>>LGR, r=row&(R-1), g=col>>6, d=col&63
// EPI 1: bias + fp32 residual, fp32 out row-major (output projection)
// Block 128x128, 4 waves 2x2, wave 64x64 = 4x4 MFMA 16x16x32. BK=32.
template <int EPI, int GH, int LGR>
__global__ __launch_bounds__(256) void gemm128(
    const bf* __restrict__ A, const bf* __restrict__ W,
    const float* __restrict__ bias, const float* __restrict__ res,
    void* __restrict__ Cout, int M, int N, int K)
{
    __shared__ __attribute__((aligned(16))) bf As[128 * 32];
    __shared__ __attribute__((aligned(16))) bf Bs[128 * 32];

    const int lane = threadIdx.x & 63;
    const int wave = threadIdx.x >> 6;
    const int lm = lane & 15;
    const int quad = lane >> 4;
    const int row0 = blockIdx.x * 128, col0 = blockIdx.y * 128;
    const int wrow = (wave >> 1) * 64, wcol = (wave & 1) * 64;

    const int sr = lane >> 2;            // 0..15
    const int sc = (lane & 3) * 8;       // elem offset 0,8,16,24
    const bf* Ag = A + (size_t)(row0 + wave * 32 + sr) * K + sc;
    const bf* Wg = W + (size_t)(col0 + wave * 32 + sr) * K + sc;
    bf* AsW = As + wave * 1024;
    bf* BsW = Bs + wave * 1024;

    f32x4 acc[4][4] = {};

    for (int k0 = 0; k0 < K; k0 += 32) {
        GLL16(Ag + k0, AsW);
        GLL16(Ag + (size_t)16 * K + k0, AsW + 512);
        GLL16(Wg + k0, BsW);
        GLL16(Wg + (size_t)16 * K + k0, BsW + 512);
        __syncthreads();

        bf16x8 a[4], b[4];
#pragma unroll
        for (int i = 0; i < 4; ++i)
            a[i] = *(const bf16x8*)(As + (wrow + i * 16 + lm) * 32 + quad * 8);
#pragma unroll
        for (int j = 0; j < 4; ++j)
            b[j] = *(const bf16x8*)(Bs + (wcol + j * 16 + lm) * 32 + quad * 8);
#pragma unroll
        for (int i = 0; i < 4; ++i)
#pragma unroll
            for (int j = 0; j < 4; ++j)
                acc[i][j] = MFMA(a[i], b[j], acc[i][j]);
        __syncthreads();
    }

    float bv[4];
#pragma unroll
    for (int j = 0; j < 4; ++j) bv[j] = bias[col0 + wcol + j * 16 + lm];

    if (EPI == 0) {
        bf* C = (bf*)Cout;
        const int g = (col0 + wcol) >> 6;
#pragma unroll
        for (int i = 0; i < 4; ++i) {
#pragma unroll
            for (int rg = 0; rg < 4; ++rg) {
                float v[4];
                float ss = 0.f;
#pragma unroll
                for (int j = 0; j < 4; ++j) {
                    const float x = acc[i][j][rg] + bv[j];
                    v[j] = x;
                    ss += x * x;
                }
                ss += __shfl_xor(ss, 1, 64);
                ss += __shfl_xor(ss, 2, 64);
                ss += __shfl_xor(ss, 4, 64);
                ss += __shfl_xor(ss, 8, 64);
                const float inv = 1.0f / fmaxf(sqrtf(ss), 1e-12f);
                const int row = row0 + wrow + i * 16 + quad * 4 + rg;
                const int bt = row >> LGR;
                const int rl = row & ((1 << LGR) - 1);
                bf* Cr = C + (((size_t)(bt * GH + g) << LGR) + rl) * 64;
#pragma unroll
                for (int j = 0; j < 4; ++j)
                    Cr[j * 16 + lm] = (bf)(v[j] * inv);
            }
        }
    } else {
        float* C = (float*)Cout;
#pragma unroll
        for (int i = 0; i < 4; ++i) {
#pragma unroll
            for (int rg = 0; rg < 4; ++rg) {
                const int row = row0 + wrow + i * 16 + quad * 4 + rg;
#pragma unroll
                for (int j = 0; j < 4; ++j) {
                    const size_t idx = (size_t)row * N + col0 + wcol + j * 16 + lm;
                    C[idx] = acc[i][j][rg] + bv[j] + res[idx];
                }
            }
        }
    }
}

// ---------------- flash-style cosine attention, NO-MAX softmax ----------------
// Scores bounded: |q.k|/8 <= 0.125 (unit vectors) -> exp never overflows, softmax
// shift term provably unnecessary -> no max pass, no online rescale, sums in regs.
// Grid 1024: blockIdx = qb*512 + bt*8 + h. Block 256 thr / 4 waves; each wave owns
// 32 q-rows (2 chunks of 16). 4 key-tiles of 128. LDS 40 KB -> 4 blocks/CU.
__global__ __launch_bounds__(256, 4) void attn(
    const bf* __restrict__ qn, const bf* __restrict__ kvn, bf* __restrict__ X)
{
    __shared__ __attribute__((aligned(16))) bf Kt[128 * 72];   // key tile [key][72]
    __shared__ __attribute__((aligned(16))) bf Vt[64 * 136];   // V^T tile [d][136]
    __shared__ __attribute__((aligned(16))) bf Ps[4][16 * 40]; // per-wave P slice

    const int qb = blockIdx.x >> 9;
    const int rb = blockIdx.x & 511;
    const int bt = rb >> 3;
    const int h = rb & 7;
    const int tid = threadIdx.x;
    const int lane = tid & 63;
    const int wave = tid >> 6;
    const int lm = lane & 15;
    const int quad = lane >> 4;

    // head-major inputs: qn (bt,h,256,64), kvn (bt,2h,512,64)
    const bf* qh = qn + ((size_t)(bt * 8 + h) * 256 + qb * 128) * 64;
    const bf* kh = kvn + (size_t)(bt * 16 + h) * 512 * 64;
    const bf* vh = kvn + (size_t)(bt * 16 + 8 + h) * 512 * 64;

    const int srow = tid >> 1;        // 0..127
    const int sseg = (tid & 1) * 32;  // 0 or 32

    f32x4 o[2][4] = {};
    float sum[2][4] = {};
    bf* Pw = &Ps[wave][0];

    for (int t = 0; t < 4; ++t) {
        // ---- stage K tile (row-major, padded) + V^T tile ----
        {
            const bf* kr = kh + (size_t)(t * 128 + srow) * 64 + sseg;
            bf* kd = Kt + srow * 72 + sseg;
#pragma unroll
            for (int j = 0; j < 4; ++j)
                *(bf16x8*)(kd + j * 8) = *(const bf16x8*)(kr + j * 8);

            const bf* vr = vh + (size_t)(t * 128 + srow) * 64 + sseg;
            bf16x8 vv[4];
#pragma unroll
            for (int j = 0; j < 4; ++j) vv[j] = *(const bf16x8*)(vr + j * 8);
#pragma unroll
            for (int j = 0; j < 4; ++j)
#pragma unroll
                for (int e = 0; e < 8; ++e)
                    Vt[(sseg + j * 8 + e) * 136 + srow] = vv[j][e];
        }
        __syncthreads();

        // ---- two 16-row q chunks ----
#pragma unroll
        for (int c = 0; c < 2; ++c) {
            const int r0 = wave * 32 + c * 16;
            const bf* qp = qh + (size_t)(r0 + lm) * 64 + quad * 8;
            const bf16x8 a0 = *(const bf16x8*)qp;
            const bf16x8 a1 = *(const bf16x8*)(qp + 32);

            f32x4 s[8];
#pragma unroll
            for (int nt = 0; nt < 8; ++nt) {
                const bf16x8 k0 = *(const bf16x8*)(&Kt[(nt * 16 + lm) * 72 + quad * 8]);
                const bf16x8 k1 = *(const bf16x8*)(&Kt[(nt * 16 + lm) * 72 + 32 + quad * 8]);
                f32x4 z = {};
                z = MFMA(a0, k0, z);
                s[nt] = MFMA(a1, k1, z);
            }

            // exp (no max needed), P slices through LDS, PV accumulate
            for (int ntp = 0; ntp < 4; ++ntp) {
#pragma unroll
                for (int tt = 0; tt < 2; ++tt)
#pragma unroll
                    for (int rr = 0; rr < 4; ++rr) {
                        const float e = __expf(s[ntp * 2 + tt][rr] * 0.125f);
                        sum[c][rr] += e;
                        Pw[(quad * 4 + rr) * 40 + tt * 16 + lm] = (bf)e;
                    }
                const bf16x8 ap = *(const bf16x8*)(&Pw[lm * 40 + quad * 8]);
#pragma unroll
                for (int dt = 0; dt < 4; ++dt) {
                    const bf16x8 bv = *(const bf16x8*)(&Vt[(dt * 16 + lm) * 136 + ntp * 32 + quad * 8]);
                    o[c][dt] = MFMA(ap, bv, o[c][dt]);
                }
            }
        }
        __syncthreads();  // Kt/Vt restaged next tile
    }

    // ---- single final reduction + normalize + store ----
#pragma unroll
    for (int c = 0; c < 2; ++c) {
        float inv[4];
#pragma unroll
        for (int rr = 0; rr < 4; ++rr) {
            float sm = sum[c][rr];
            sm += __shfl_xor(sm, 1, 64);
            sm += __shfl_xor(sm, 2, 64);
            sm += __shfl_xor(sm, 4, 64);
            sm += __shfl_xor(sm, 8, 64);
            inv[rr] = 1.0f / sm;
        }
        bf* Xp = X + ((size_t)bt * 256 + qb * 128 + wave * 32 + c * 16) * 512 + h * 64;
#pragma unroll
        for (int dt = 0; dt < 4; ++dt)
#pragma unroll
            for (int rr = 0; rr < 4; ++rr)
                Xp[(size_t)(quad * 4 + rr) * 512 + dt * 16 + lm] = (bf)(o[c][dt][rr] * inv[rr]);
    }
}

extern "C" void kernel_launch(void* const* d_in, const int* in_sizes, int n_in,
                              void* d_out, int out_size, void* d_ws, size_t ws_size,
                              hipStream_t stream)
{
    const float* q   = (const float*)d_in[0];  // (8,8,256,512) fp32
    const float* kv  = (const float*)d_in[1];  // (8,8,512,512) fp32
    const float* Wq  = (const float*)d_in[2];  // (512,512) fp32
    const float* bq  = (const float*)d_in[3];  // (512) fp32
    const float* Wkv = (const float*)d_in[4];  // (1024,512) fp32
    const float* bkv = (const float*)d_in[5];  // (1024) fp32
    const float* Wm  = (const float*)d_in[6];  // (512,512) fp32
    const float* bm  = (const float*)d_in[7];  // (512) fp32
    float* out = (float*)d_out;                // (8,8,256,512) fp32 (32 MiB)

    char* ws = (char*)d_ws;
    bf* kvb = (bf*)ws;                          // [0,32 MiB)  kv bf16 (dead after KV-proj)
    bf* kvn = (bf*)(ws + (size_t)(32 << 20));   // [32,96 MiB) normalized kv heads (head-major)
    bf* wqb = (bf*)ws;                          // [0,0.5 MiB) Wq bf16 (after kvb dead)
    bf* wmb = (bf*)(ws + (size_t)(16 << 20));   // [16,16.5 MiB) Wm bf16 (after kvb dead)
    bf* X   = (bf*)ws;                          // [0,16 MiB)  attn output (after wqb dead)
    char* dob = (char*)d_out;
    bf* wkvb = (bf*)dob;                        // d_out[0,1 MiB) Wkv bf16 (dead after KV-proj)
    bf* qb   = (bf*)dob;                        // d_out[0,16 MiB) q bf16 (overwrites wkvb)
    bf* qn   = (bf*)(dob + (size_t)(16 << 20)); // d_out[16,32 MiB) normalized q heads (head-major)

    // 1. kv + Wkv -> bf16
    cvt2<<<dim3(8448), 256, 0, stream>>>(kv, kvb, 2097152, Wkv, wkvb, 65536);
    // 2. KV projection + bias + fused L2-norm -> head-major kvn (bt,16,512,64)
    gemm128<0, 16, 9><<<dim3(256, 8), 256, 0, stream>>>(kvb, wkvb, bkv, nullptr, kvn, 32768, 1024, 512);
    // 3. q, Wq, Wm -> bf16
    cvt3<<<dim3(4352), 256, 0, stream>>>(q, qb, 1048576, Wq, wqb, 32768, Wm, wmb, 32768);
    // 4. Q projection + bias + fused L2-norm -> head-major qn (bt,8,256,64)
    gemm128<0, 8, 8><<<dim3(128, 4), 256, 0, stream>>>(qb, wqb, bq, nullptr, qn, 16384, 512, 512);
    // 5. no-max flash cosine attention
    attn<<<dim3(1024), 256, 0, stream>>>(qn, kvn, X);
    // 6. output projection + bias + fp32 residual -> fp32 out (rewrites all of d_out)
    gemm128<1, 0, 0><<<dim3(128, 4), 256, 0, stream>>>(X, wmb, bm, q, out, 16384, 512, 512);
}